// Round 1
// baseline (114.587 us; speedup 1.0000x reference)
//
#include <hip/hip_runtime.h>
#include <hip/hip_bf16.h>

#define N_    16
#define IC_   512
#define OC_   512
#define SDIM_ 512
#define H_    32
#define W_    32
#define HW_   1024

#define FC_SCALER 0.04419417382415922f          /* 1/sqrt(512) */
#define WS_       0.014731391274719738f         /* 1/sqrt(4608) */
#define WS2_      (1.0f/4608.0f)

typedef __attribute__((__ext_vector_type__(8)))  __bf16 bf16x8;
typedef __attribute__((__ext_vector_type__(16))) float  f32x16;
typedef __attribute__((__ext_vector_type__(4)))  int    i32x4;

__device__ __forceinline__ unsigned short f2bf(float f) {
    unsigned int u = __builtin_bit_cast(unsigned int, f);
    unsigned int r = (u + 0x7FFFu + ((u >> 16) & 1u)) >> 16;
    return (unsigned short)r;
}

// ---------------- K1: mod[n][c] = style[n]·fcw[c]*FC_SCALER + fcb[c] + 1 ----------------
__global__ void k_mod(const float* __restrict__ style, const float* __restrict__ fcw,
                      const float* __restrict__ fcb, float* __restrict__ mod) {
    int gid = blockIdx.x * blockDim.x + threadIdx.x;
    int wid = gid >> 6, lane = gid & 63;
    if (wid >= N_ * IC_) return;
    int n = wid >> 9, c = wid & 511;
    const float4* sp = (const float4*)(style + n * SDIM_);
    const float4* wp = (const float4*)(fcw + (size_t)c * SDIM_);
    float acc = 0.f;
    for (int i = lane; i < SDIM_ / 4; i += 64) {
        float4 a = sp[i], b = wp[i];
        acc += a.x*b.x + a.y*b.y + a.z*b.z + a.w*b.w;
    }
#pragma unroll
    for (int off = 32; off; off >>= 1) acc += __shfl_xor(acc, off);
    if (lane == 0) mod[wid] = acc * FC_SCALER + fcb[c] + 1.0f;
}

// ---------------- K2: wt[t][oc][ic] = bf16(weight[oc][ic][t]);  wsq[oc][ic] = sum_t w^2 --
__global__ void k_wprep(const float* __restrict__ w, unsigned short* __restrict__ wt,
                        float* __restrict__ wsq) {
    int tid = blockIdx.x * blockDim.x + threadIdx.x;   // 0 .. OC*IC-1
    int oc = tid >> 9, ic = tid & 511;
    float s = 0.f;
#pragma unroll
    for (int t = 0; t < 9; t++) {
        float v = w[(size_t)tid * 9 + t];
        s += v * v;
        wt[((size_t)(t * OC_ + oc)) * IC_ + ic] = f2bf(v);
    }
    wsq[tid] = s;
}

// ---------------- K3: demod_ws[n][oc] = WS * rsqrt(WS2*sum_ic mod^2*wsq + 1e-8) ---------
__global__ void k_demod(const float* __restrict__ mod, const float* __restrict__ wsq,
                        float* __restrict__ demod_ws) {
    int gid = blockIdx.x * blockDim.x + threadIdx.x;
    int wid = gid >> 6, lane = gid & 63;
    if (wid >= N_ * OC_) return;
    int n = wid >> 9, oc = wid & 511;
    const float4* mp = (const float4*)(mod + n * IC_);
    const float4* qp = (const float4*)(wsq + (size_t)oc * IC_);
    float acc = 0.f;
    for (int i = lane; i < IC_ / 4; i += 64) {
        float4 m = mp[i], q = qp[i];
        acc += m.x*m.x*q.x + m.y*m.y*q.y + m.z*m.z*q.z + m.w*m.w*q.w;
    }
#pragma unroll
    for (int off = 32; off; off >>= 1) acc += __shfl_xor(acc, off);
    if (lane == 0) {
        float s = WS2_ * acc + 1e-8f;
        demod_ws[wid] = WS_ / sqrtf(s);
    }
}

// ---------------- K4: xm[n][y][x][ic] = bf16(x[n][ic][y][x] * mod[n][ic])  (NHWC) -------
__global__ void k_premod(const float* __restrict__ x, const float* __restrict__ mod,
                         unsigned short* __restrict__ xm) {
    __shared__ __align__(16) unsigned short t_lds[64][80];
    int bx = blockIdx.x;                 // n(16) * hwt(16) * ict(8)
    int n = bx >> 7, hwt = (bx >> 3) & 15, ict = bx & 7;
    int hw0 = hwt * 64, ic0 = ict * 64;
    int tid = threadIdx.x, lane = tid & 63, ty = tid >> 6;
#pragma unroll
    for (int jj = 0; jj < 16; jj++) {
        int icl = ty * 16 + jj;
        float v = x[(size_t)(n * IC_ + ic0 + icl) * HW_ + hw0 + lane]
                  * mod[n * IC_ + ic0 + icl];
        t_lds[lane][icl] = f2bf(v);
    }
    __syncthreads();
#pragma unroll
    for (int rep = 0; rep < 2; rep++) {
        int hwl = rep * 32 + (tid >> 3);
        int icl8 = (tid & 7) * 8;
        i32x4 v = *(const i32x4*)&t_lds[hwl][icl8];
        *(i32x4*)(xm + ((size_t)(n * HW_ + hw0 + hwl) * IC_ + ic0 + icl8)) = v;
    }
}

// ---------------- K5: per-sample conv via implicit GEMM, bf16 MFMA 32x32x16 -------------
// block: 128 oc x 128 spatial (4 image rows), 256 threads = 4 waves (2x2),
// wave tile 64 oc x 64 sp = 2x2 frags of 32x32. K-loop: ic chunks of 64, 9 taps inside.
#define BLK_OC 128
__global__ __launch_bounds__(256, 2)
void k_conv(const unsigned short* __restrict__ xm, const unsigned short* __restrict__ wt,
            const float* __restrict__ demod_ws, float* __restrict__ out) {
    __shared__ __align__(16) unsigned short xt[6 * 34 * 64];     // [rr][cp][ic] swizzled
    __shared__ __align__(16) unsigned short wbuf[2][128 * 64];   // [oc][ic] swizzled
    __shared__ float s_demod[128];

    int bx = blockIdx.x;                       // n(16) * octile(4) * sptile(8)
    int n = bx >> 5, octile = (bx >> 3) & 3, sptile = bx & 7;
    int oc0 = octile * BLK_OC, y0 = sptile * 4;
    int tid = threadIdx.x, lane = tid & 63, wid = tid >> 6;
    int wr = wid >> 1, wc = wid & 1;

    if (tid < 128) s_demod[tid] = demod_ws[n * OC_ + oc0 + tid];

    f32x16 acc[2][2] = {};

    const unsigned short* xbase = xm + (size_t)n * HW_ * IC_;

#pragma unroll 1
    for (int icc = 0; icc < IC_ / 64; icc++) {
        int ic0 = icc * 64;
        // ---- stage x halo tile [6 rows][34 cols][64 ic], zero-padded, swizzled ----
        for (int idx = tid; idx < 6 * 34 * 8; idx += 256) {
            int rc = idx >> 3, icl8 = (idx & 7) * 8;
            int rr = rc / 34, cp = rc - rr * 34;
            int yy = y0 - 1 + rr, xx = cp - 1;
            i32x4 v = {};
            if ((unsigned)yy < 32u && (unsigned)xx < 32u)
                v = *(const i32x4*)(xbase + ((size_t)(yy * W_ + xx) * IC_ + ic0 + icl8));
            int a = (rc * 128 + icl8 * 2) ^ ((rc & 7) << 4);
            *(i32x4*)((char*)xt + a) = v;
        }
        // ---- stage tap-0 weights into wbuf[0] ----
        {
            const unsigned short* wsrc = wt + (size_t)oc0 * IC_ + ic0;
#pragma unroll
            for (int k = 0; k < 4; k++) {
                int c = tid + k * 256;
                int ocl = c >> 3, icl8 = (c & 7) * 8;
                i32x4 v = *(const i32x4*)(wsrc + (size_t)ocl * IC_ + icl8);
                int a = (ocl * 128 + icl8 * 2) ^ ((ocl & 7) << 4);
                *(i32x4*)((char*)wbuf[0] + a) = v;
            }
        }
        __syncthreads();

#pragma unroll
        for (int t = 0; t < 9; t++) {
            i32x4 wreg[4];
            if (t < 8) {   // prefetch next tap's weights into regs (overlaps MFMA)
                const unsigned short* wsrc =
                    wt + ((size_t)((t + 1) * OC_ + oc0)) * IC_ + ic0;
#pragma unroll
                for (int k = 0; k < 4; k++) {
                    int c = tid + k * 256;
                    int ocl = c >> 3, icl8 = (c & 7) * 8;
                    wreg[k] = *(const i32x4*)(wsrc + (size_t)ocl * IC_ + icl8);
                }
            }
            int dy = t / 3, dx = t % 3;
            const unsigned short* wb = wbuf[t & 1];
#pragma unroll
            for (int kk = 0; kk < 4; kk++) {
                int koff = kk * 16 + (lane >> 5) * 8;
                bf16x8 af[2], bfr[2];
#pragma unroll
                for (int fo = 0; fo < 2; fo++) {
                    int ocl = wr * 64 + fo * 32 + (lane & 31);
                    int a = (ocl * 128 + koff * 2) ^ ((ocl & 7) << 4);
                    af[fo] = *(const bf16x8*)((const char*)wb + a);
                }
#pragma unroll
                for (int fs = 0; fs < 2; fs++) {
                    int rr = wc * 2 + fs + dy;
                    int cp = (lane & 31) + dx;
                    int rc = rr * 34 + cp;
                    int a = (rc * 128 + koff * 2) ^ ((rc & 7) << 4);
                    bfr[fs] = *(const bf16x8*)((const char*)xt + a);
                }
#pragma unroll
                for (int fo = 0; fo < 2; fo++)
#pragma unroll
                    for (int fs = 0; fs < 2; fs++)
                        acc[fo][fs] = __builtin_amdgcn_mfma_f32_32x32x16_bf16(
                            af[fo], bfr[fs], acc[fo][fs], 0, 0, 0);
            }
            if (t < 8) {   // write prefetched weights into the other buffer
#pragma unroll
                for (int k = 0; k < 4; k++) {
                    int c = tid + k * 256;
                    int ocl = c >> 3, icl8 = (c & 7) * 8;
                    int a = (ocl * 128 + icl8 * 2) ^ ((ocl & 7) << 4);
                    *(i32x4*)((char*)wbuf[(t + 1) & 1] + a) = wreg[k];
                }
            }
            __syncthreads();
        }
    }

    // ---- epilogue: scale by demod*WS, store fp32 NCHW ----
    int xcol = lane & 31;
#pragma unroll
    for (int fo = 0; fo < 2; fo++) {
#pragma unroll
        for (int fs = 0; fs < 2; fs++) {
            int y = y0 + wc * 2 + fs;
#pragma unroll
            for (int r = 0; r < 16; r++) {
                int row = (r & 3) + 8 * (r >> 2) + 4 * (lane >> 5);
                int ocl = wr * 64 + fo * 32 + row;
                float v = acc[fo][fs][r] * s_demod[ocl];
                out[((size_t)(n * OC_ + oc0 + ocl) * H_ + y) * W_ + xcol] = v;
            }
        }
    }
}

extern "C" void kernel_launch(void* const* d_in, const int* in_sizes, int n_in,
                              void* d_out, int out_size, void* d_ws, size_t ws_size,
                              hipStream_t stream) {
    const float* x      = (const float*)d_in[0];
    const float* style  = (const float*)d_in[1];
    const float* weight = (const float*)d_in[2];
    const float* fcw    = (const float*)d_in[3];
    const float* fcb    = (const float*)d_in[4];
    float* out = (float*)d_out;

    char* ws = (char*)d_ws;
    float*          mod   = (float*)ws;                          // 32 KB
    float*          demod = (float*)(ws + 32768);                // 32 KB
    float*          wsq   = (float*)(ws + 65536);                // 1 MB
    unsigned short* wtb   = (unsigned short*)(ws + 65536 + 1048576);           // 4.5 MB
    unsigned short* xmb   = (unsigned short*)(ws + 65536 + 1048576 + 4718592); // 16 MB

    k_mod   <<<2048, 256, 0, stream>>>(style, fcw, fcb, mod);
    k_wprep <<<1024, 256, 0, stream>>>(weight, wtb, wsq);
    k_demod <<<2048, 256, 0, stream>>>(mod, wsq, demod);
    k_premod<<<2048, 256, 0, stream>>>(x, mod, xmb);
    k_conv  <<<512,  256, 0, stream>>>(xmb, wtb, demod, out);
}